// Round 4
// baseline (953.904 us; speedup 1.0000x reference)
//
#include <hip/hip_runtime.h>

// Problem constants (fixed by setup_inputs)
#define BB 8
#define DD 32
#define HH 512
#define WW 512
#define HWSZ (HH*WW)          // 262144 = 2^18
#define NPIX (BB*HWSZ)        // 2097152
#define CC 19
#define EPSF 1e-8f

// Accumulator layout: per class 65 floats: [0..31]=sum(x), [32..63]=sum(x/|x|), [64]=count
#define CSTRIDE 65
#define ACCSZ (CC*CSTRIDE)    // 1235 floats
#define NCOPY 8               // LDS copies: 8 lanes/copy

#define NBLK1 2048
#define NTHR1 256
// 2048*256 = 524288 threads -> 4 pixels/thread

__global__ void k0_zero(float* __restrict__ acc)
{
    int i = blockIdx.x * 256 + threadIdx.x;
    if (i < ACCSZ) acc[i] = 0.f;
}

__global__ __launch_bounds__(NTHR1, 4) void k1_accum(
    const float* __restrict__ in, const int* __restrict__ tgt,
    float* __restrict__ acc)
{
    __shared__ float lds[NCOPY * ACCSZ];   // 39520 B -> 4 blocks/CU (LDS-limited)
    const int t = threadIdx.x;

    for (int i = t; i < NCOPY * ACCSZ; i += NTHR1) lds[i] = 0.f;
    __syncthreads();

    float* my = lds + (t & (NCOPY - 1)) * ACCSZ;

    const int T = NBLK1 * NTHR1;                 // 524288
    int pix = blockIdx.x * NTHR1 + t;

    #pragma unroll 1
    for (int k = 0; k < NPIX / T; k++, pix += T) {
        int b  = pix >> 18;
        int hw = pix & (HWSZ - 1);
        const float* base = in + (((size_t)b * DD) << 18) + hw;

        int c = tgt[pix];                         // coalesced dword

        // 32 independent coalesced loads -> registers (32 VGPRs), ONE wait
        float v[DD];
        #pragma unroll
        for (int d = 0; d < DD; d++) v[d] = base[(size_t)d << 18];

        float ss = 0.f;
        #pragma unroll
        for (int d = 0; d < DD; d++) ss = fmaf(v[d], v[d], ss);
        float inv = rsqrtf(fmaxf(ss, 1e-30f));

        // fire-and-forget LDS fp atomics from registers
        float* a = my + c * CSTRIDE;
        #pragma unroll
        for (int d = 0; d < DD; d++) {
            unsafeAtomicAdd(a + d,      v[d]);
            unsafeAtomicAdd(a + 32 + d, v[d] * inv);
        }
        unsafeAtomicAdd(a + 64, 1.f);
    }
    __syncthreads();

    // fold 8 LDS copies -> device-scope HW atomic add into the global accumulator
    for (int i = t; i < ACCSZ; i += NTHR1) {
        float s = 0.f;
        #pragma unroll
        for (int kk = 0; kk < NCOPY; kk++) s += lds[kk * ACCSZ + i];
        unsafeAtomicAdd(acc + i, s);
    }
}

// Final: tiny 19-class epilogue. 1 block x 256 threads, deterministic reduction.
__global__ void k3_final(const float* __restrict__ gacc, float* __restrict__ out)
{
    __shared__ float acc[ACCSZ];
    __shared__ float cn[CC];
    __shared__ float pres[CC];
    __shared__ float red[256];
    const int t = threadIdx.x;

    for (int i = t; i < ACCSZ; i += 256) acc[i] = gacc[i];
    __syncthreads();

    float part = 0.f;

    // cosine is scale-invariant in the center, so raw sums replace centers:
    // seg_cos_c = (sums_c . S_c) / |sums_c|,  S_c = sum_{n in c} x_n/|x_n|
    if (t < CC) {
        const float* a = acc + t * CSTRIDE;
        float n2 = 0.f, dotS = 0.f;
        #pragma unroll
        for (int d = 0; d < DD; d++) {
            n2   = fmaf(a[d], a[d], n2);
            dotS = fmaf(a[d], a[32 + d], dotS);
        }
        float count = a[64];
        float den   = fmaxf(count, 1.f);
        float norm  = sqrtf(n2);
        cn[t]   = norm;
        pres[t] = (count > 0.f) ? 1.f : 0.f;
        float segcos = (norm > 0.f) ? (dotS / norm) : 0.f;
        part += (count > 0.f) ? (1.f - segcos / den) : 0.f;
    }
    __syncthreads();

    // diff loss: 19x19 pair terms on raw sums (denominators cancel in cosine)
    for (int p = t; p < CC * CC; p += 256) {
        int i = p / CC, j = p % CC;
        const float* ai = acc + i * CSTRIDE;
        const float* aj = acc + j * CSTRIDE;
        float dot = 0.f;
        #pragma unroll
        for (int d = 0; d < DD; d++) dot = fmaf(ai[d], aj[d], dot);
        float dd  = fmaxf(cn[i] * cn[j], EPSF);
        float cs  = dot / dd;
        float term = (i == j) ? (1.f - cs) : fmaxf(cs, 0.f);
        part += pres[i] * term * (1.f / (float)CC);
    }

    red[t] = part;
    __syncthreads();
    #pragma unroll
    for (int s = 128; s > 0; s >>= 1) {
        if (t < s) red[t] += red[t + s];
        __syncthreads();
    }
    if (t == 0) out[0] = red[0];
}

extern "C" void kernel_launch(void* const* d_in, const int* in_sizes, int n_in,
                              void* d_out, int out_size, void* d_ws, size_t ws_size,
                              hipStream_t stream)
{
    const float* in  = (const float*)d_in[0];
    const int*   tgt = (const int*)d_in[1];
    float* out = (float*)d_out;
    float* acc = (float*)d_ws;                // 1235 floats ~ 5 KB

    hipLaunchKernelGGL(k0_zero, dim3((ACCSZ + 255) / 256), dim3(256), 0, stream, acc);
    hipLaunchKernelGGL(k1_accum, dim3(NBLK1), dim3(NTHR1), 0, stream, in, tgt, acc);
    hipLaunchKernelGGL(k3_final, dim3(1), dim3(256), 0, stream, acc, out);
}